// Round 1
// baseline (508.267 us; speedup 1.0000x reference)
//
#include <hip/hip_runtime.h>
#include <hip/hip_bf16.h>
#include <type_traits>

#define DEV __device__ __forceinline__

typedef short bf16x8 __attribute__((ext_vector_type(8)));
typedef float f32x4 __attribute__((ext_vector_type(4)));

static DEV unsigned short f2bf(float f) {
  unsigned u = __builtin_bit_cast(unsigned, f);
  u += 0x7FFFu + ((u >> 16) & 1u);
  return (unsigned short)(u >> 16);
}

// ---------------- W [K][N] f32 -> Wt [N][K] bf16 (transpose + convert) ----------------
__global__ __launch_bounds__(256) void wtrans(const float* __restrict__ W,
                                              unsigned short* __restrict__ Wt) {
  __shared__ __align__(16) unsigned short T[64][72];
  const int tid = threadIdx.x;
  const int k0 = blockIdx.x * 64, n0 = blockIdx.y * 64;
  const int r = tid >> 4, c4 = (tid & 15) * 4;
  for (int j = 0; j < 4; ++j) {
    int row = j * 16 + r;
    float4 v = *(const float4*)&W[(size_t)(k0 + row) * 1024 + n0 + c4];
    ushort4 w;
    w.x = f2bf(v.x); w.y = f2bf(v.y); w.z = f2bf(v.z); w.w = f2bf(v.w);
    *(ushort4*)&T[row][c4] = w;
  }
  __syncthreads();
  for (int j = 0; j < 4; ++j) {
    int n = j * 16 + r;
    ushort4 w;
    w.x = T[c4 + 0][n]; w.y = T[c4 + 1][n]; w.z = T[c4 + 2][n]; w.w = T[c4 + 3][n];
    *(ushort4*)&Wt[(size_t)(n0 + n) * 1024 + k0 + c4] = w;
  }
}

// ---------------- GEMM: Y[M][1024] = X[M][1024] @ W + bias ----------------
// Wt is bf16 [N][K] (pre-transposed). InT = float|ushort(bf16), OutT = float|ushort(bf16).
template <typename InT, typename OutT>
__global__ __launch_bounds__(256) void gemm_bias(const InT* __restrict__ X,
                                                 const unsigned short* __restrict__ Wt,
                                                 const float* __restrict__ bias,
                                                 OutT* __restrict__ Y) {
  constexpr int KP = 72;  // padded K pitch (bf16 elems): 144B rows, 16B aligned
  __shared__ __align__(16) unsigned short As[128 * KP];
  __shared__ __align__(16) unsigned short Bs[128 * KP];
  const int tid = threadIdx.x, lane = tid & 63, wid = tid >> 6;
  const int m0 = blockIdx.x * 128, n0 = blockIdx.y * 128;
  const int wm = (wid >> 1) * 64, wn = (wid & 1) * 64;
  f32x4 acc[4][4] = {};

  for (int k0 = 0; k0 < 1024; k0 += 64) {
    __syncthreads();
    {
      // stage A: 128 rows x 64 k, convert to bf16
      const int r = tid >> 4, c4 = (tid & 15) * 4;
      for (int j = 0; j < 8; ++j) {
        const int row = j * 16 + r;
        ushort4 w;
        if constexpr (std::is_same_v<InT, float>) {
          float4 v = *(const float4*)&X[(size_t)(m0 + row) * 1024 + k0 + c4];
          w.x = f2bf(v.x); w.y = f2bf(v.y); w.z = f2bf(v.z); w.w = f2bf(v.w);
        } else {
          w = *(const ushort4*)&X[(size_t)(m0 + row) * 1024 + k0 + c4];
        }
        *(ushort4*)&As[row * KP + c4] = w;
      }
      // stage B: Wt rows (n-major), already bf16, b128 copies
      const int r2 = tid >> 3, c8 = (tid & 7) * 8;
      for (int j = 0; j < 4; ++j) {
        const int n = j * 32 + r2;
        *(uint4*)&Bs[n * KP + c8] = *(const uint4*)&Wt[(size_t)(n0 + n) * 1024 + k0 + c8];
      }
    }
    __syncthreads();
    for (int kk = 0; kk < 2; ++kk) {
      const int kb = kk * 32 + (lane >> 4) * 8;
      bf16x8 af[4], bfr[4];
      for (int i = 0; i < 4; ++i)
        af[i] = *(const bf16x8*)&As[(wm + i * 16 + (lane & 15)) * KP + kb];
      for (int i = 0; i < 4; ++i)
        bfr[i] = *(const bf16x8*)&Bs[(wn + i * 16 + (lane & 15)) * KP + kb];
      for (int mi = 0; mi < 4; ++mi)
        for (int ni = 0; ni < 4; ++ni)
          acc[mi][ni] =
              __builtin_amdgcn_mfma_f32_16x16x32_bf16(af[mi], bfr[ni], acc[mi][ni], 0, 0, 0);
    }
  }
  for (int ni = 0; ni < 4; ++ni) {
    const int col = n0 + wn + ni * 16 + (lane & 15);
    const float bv = bias[col];
    for (int mi = 0; mi < 4; ++mi) {
      const int row = m0 + wm + mi * 16 + (lane >> 4) * 4;
      for (int r = 0; r < 4; ++r) {
        float v = acc[mi][ni][r] + bv;
        if constexpr (std::is_same_v<OutT, float>)
          Y[(size_t)(row + r) * 1024 + col] = v;
        else
          Y[(size_t)(row + r) * 1024 + col] = f2bf(v);
      }
    }
  }
}

// ---------------- causal flash attention ----------------
// Qb/Kb/Vb: bf16 [B*S][1024] (projected). Ob: bf16 [B*S][1024].
// grid: (S/128, B*H). block: 256 (4 waves x 32 q-rows each). KVBLK=32.
__global__ __launch_bounds__(256) void attn_fwd(const unsigned short* __restrict__ Qb,
                                                const unsigned short* __restrict__ Kb,
                                                const unsigned short* __restrict__ Vb,
                                                unsigned short* __restrict__ Ob) {
  constexpr int KP = 72, VP = 40, PP = 40;
  __shared__ __align__(16) unsigned short Ks[32 * KP];    // [kv][d]
  __shared__ __align__(16) unsigned short Vts[64 * VP];   // [dv][kv] (transposed)
  __shared__ __align__(16) unsigned short Ps[4][32 * PP]; // per-wave P tile [q][kv]
  const int tid = threadIdx.x, lane = tid & 63, wid = tid >> 6;
  const int q0 = blockIdx.x * 128;
  const int bh = blockIdx.y, b = bh >> 4, h = bh & 15;
  const size_t rowbase = (size_t)b * 2048;
  const int col0 = h * 64;

  // Q fragments in registers (wave owns rows q0+wid*32 .. +31)
  bf16x8 qf[2][2];
  for (int mt = 0; mt < 2; ++mt)
    for (int kk = 0; kk < 2; ++kk) {
      int qrow = q0 + wid * 32 + mt * 16 + (lane & 15);
      qf[mt][kk] =
          *(const bf16x8*)&Qb[(rowbase + qrow) * 1024 + col0 + kk * 32 + (lane >> 4) * 8];
    }

  f32x4 o[2][4] = {};
  float mrow[2][4], lrow[2][4];
  for (int mt = 0; mt < 2; ++mt)
    for (int r = 0; r < 4; ++r) { mrow[mt][r] = -3.0e38f; lrow[mt][r] = 0.f; }

  const int myqmax = q0 + wid * 32 + 31;
  for (int kv0 = 0; kv0 < q0 + 128; kv0 += 32) {
    __syncthreads();
    {
      // stage K tile [32][64]
      const int r = tid >> 3, c8 = (tid & 7) * 8;
      *(uint4*)&Ks[r * KP + c8] =
          *(const uint4*)&Kb[(rowbase + kv0 + r) * 1024 + col0 + c8];
      // stage V transposed: thread handles kv pair {2*kvp, 2*kvp+1} x 4 dv
      const int dv0 = (tid & 15) * 4, kvp = tid >> 4;
      ushort4 va = *(const ushort4*)&Vb[(rowbase + kv0 + 2 * kvp) * 1024 + col0 + dv0];
      ushort4 vb2 = *(const ushort4*)&Vb[(rowbase + kv0 + 2 * kvp + 1) * 1024 + col0 + dv0];
      unsigned short a_[4] = {va.x, va.y, va.z, va.w};
      unsigned short b_[4] = {vb2.x, vb2.y, vb2.z, vb2.w};
      for (int i = 0; i < 4; ++i) {
        unsigned pk = (unsigned)a_[i] | ((unsigned)b_[i] << 16);
        *(unsigned*)&Vts[(dv0 + i) * VP + 2 * kvp] = pk;
      }
    }
    __syncthreads();
    if (kv0 > myqmax) continue;  // no barriers below: safe, keeps block barrier count aligned

    // QK^T: S[32 q][32 kv]
    f32x4 s[2][2] = {};
    bf16x8 kf[2][2];
    for (int nt = 0; nt < 2; ++nt)
      for (int kk = 0; kk < 2; ++kk)
        kf[nt][kk] =
            *(const bf16x8*)&Ks[(nt * 16 + (lane & 15)) * KP + kk * 32 + (lane >> 4) * 8];
    for (int mt = 0; mt < 2; ++mt)
      for (int nt = 0; nt < 2; ++nt)
        for (int kk = 0; kk < 2; ++kk)
          s[mt][nt] =
              __builtin_amdgcn_mfma_f32_16x16x32_bf16(qf[mt][kk], kf[nt][kk], s[mt][nt], 0, 0, 0);

    // scale + causal mask
    const int qrb = q0 + wid * 32 + (lane >> 4) * 4;
    const int kcb = kv0 + (lane & 15);
    for (int mt = 0; mt < 2; ++mt)
      for (int nt = 0; nt < 2; ++nt)
        for (int r = 0; r < 4; ++r) {
          float v = s[mt][nt][r] * 0.125f;
          if (kcb + nt * 16 > qrb + mt * 16 + r) v = -1.0e30f;
          s[mt][nt][r] = v;
        }

    // online softmax (row stats live in all 16 lanes of each row group)
    for (int mt = 0; mt < 2; ++mt) {
      for (int r = 0; r < 4; ++r) {
        float tmax = fmaxf(s[mt][0][r], s[mt][1][r]);
        for (int msk = 1; msk < 16; msk <<= 1) tmax = fmaxf(tmax, __shfl_xor(tmax, msk, 64));
        float mnew = fmaxf(mrow[mt][r], tmax);
        float alpha = exp2f((mrow[mt][r] - mnew) * 1.44269504f);
        mrow[mt][r] = mnew;
        float rs = 0.f;
        for (int nt = 0; nt < 2; ++nt) {
          float p = exp2f((s[mt][nt][r] - mnew) * 1.44269504f);
          s[mt][nt][r] = p;
          rs += p;
        }
        for (int msk = 1; msk < 16; msk <<= 1) rs += __shfl_xor(rs, msk, 64);
        lrow[mt][r] = lrow[mt][r] * alpha + rs;
        for (int nv = 0; nv < 4; ++nv) o[mt][nv][r] *= alpha;
      }
      // P (D-layout) -> per-wave LDS, to be re-read in A-layout
      for (int nt = 0; nt < 2; ++nt)
        for (int r = 0; r < 4; ++r)
          Ps[wid][(mt * 16 + (lane >> 4) * 4 + r) * PP + nt * 16 + (lane & 15)] =
              f2bf(s[mt][nt][r]);
    }

    // PV: O += P[32q][32kv] @ V[32kv][64dv]
    for (int mt = 0; mt < 2; ++mt) {
      bf16x8 pa = *(const bf16x8*)&Ps[wid][(mt * 16 + (lane & 15)) * PP + (lane >> 4) * 8];
      for (int nv = 0; nv < 4; ++nv) {
        bf16x8 vf = *(const bf16x8*)&Vts[(nv * 16 + (lane & 15)) * VP + (lane >> 4) * 8];
        o[mt][nv] = __builtin_amdgcn_mfma_f32_16x16x32_bf16(pa, vf, o[mt][nv], 0, 0, 0);
      }
    }
  }

  // epilogue: O / l -> bf16
  for (int mt = 0; mt < 2; ++mt)
    for (int r = 0; r < 4; ++r) {
      float inv = 1.0f / lrow[mt][r];
      int qrow = q0 + wid * 32 + mt * 16 + (lane >> 4) * 4 + r;
      for (int nv = 0; nv < 4; ++nv)
        Ob[(rowbase + qrow) * 1024 + col0 + nv * 16 + (lane & 15)] =
            f2bf(o[mt][nv][r] * inv);
    }
}

extern "C" void kernel_launch(void* const* d_in, const int* in_sizes, int n_in,
                              void* d_out, int out_size, void* d_ws, size_t ws_size,
                              hipStream_t stream) {
  const float* Q  = (const float*)d_in[0];
  const float* K  = (const float*)d_in[1];
  const float* V  = (const float*)d_in[2];
  // d_in[3] = mask: known causal tril, applied analytically in attn_fwd
  const float* Wq = (const float*)d_in[4];
  const float* bq = (const float*)d_in[5];
  const float* Wk = (const float*)d_in[6];
  const float* bk = (const float*)d_in[7];
  const float* Wv = (const float*)d_in[8];
  const float* bv = (const float*)d_in[9];
  const float* Wo = (const float*)d_in[10];
  const float* bo = (const float*)d_in[11];
  float* out = (float*)d_out;

  const size_t MB = 1024 * 1024;
  char* ws = (char*)d_ws;
  unsigned short* qb  = (unsigned short*)(ws + 0 * MB);   // 16MB bf16 [8192][1024]
  unsigned short* kb  = (unsigned short*)(ws + 16 * MB);
  unsigned short* vbf = (unsigned short*)(ws + 32 * MB);
  unsigned short* ab  = (unsigned short*)(ws + 48 * MB);  // attention out
  unsigned short* wtq = (unsigned short*)(ws + 64 * MB);  // 2MB each
  unsigned short* wtk = (unsigned short*)(ws + 66 * MB);
  unsigned short* wtv = (unsigned short*)(ws + 68 * MB);
  unsigned short* wto = (unsigned short*)(ws + 70 * MB);

  dim3 tg(16, 16);
  wtrans<<<tg, 256, 0, stream>>>(Wq, wtq);
  wtrans<<<tg, 256, 0, stream>>>(Wk, wtk);
  wtrans<<<tg, 256, 0, stream>>>(Wv, wtv);
  wtrans<<<tg, 256, 0, stream>>>(Wo, wto);

  dim3 gg(64, 8);  // M/128, N/128
  gemm_bias<float, unsigned short><<<gg, 256, 0, stream>>>(Q, wtq, bq, qb);
  gemm_bias<float, unsigned short><<<gg, 256, 0, stream>>>(K, wtk, bk, kb);
  gemm_bias<float, unsigned short><<<gg, 256, 0, stream>>>(V, wtv, bv, vbf);

  dim3 ag(16, 64);  // S/128, B*H
  attn_fwd<<<ag, 256, 0, stream>>>(qb, kb, vbf, ab);

  gemm_bias<unsigned short, float><<<gg, 256, 0, stream>>>(ab, wto, bo, out);
}

// Round 2
// 300.984 us; speedup vs baseline: 1.6887x; 1.6887x over previous
//
#include <hip/hip_runtime.h>
#include <hip/hip_bf16.h>
#include <type_traits>

#define DEV __device__ __forceinline__

typedef short bf16x8 __attribute__((ext_vector_type(8)));
typedef float f32x4 __attribute__((ext_vector_type(4)));
typedef float f32x16 __attribute__((ext_vector_type(16)));
typedef unsigned u32x4 __attribute__((ext_vector_type(4)));

static DEV unsigned short f2bf(float f) {
  unsigned u = __builtin_bit_cast(unsigned, f);
  u += 0x7FFFu + ((u >> 16) & 1u);
  return (unsigned short)(u >> 16);
}

static DEV unsigned cvtpk(float lo, float hi) {
  unsigned d;
  asm("v_cvt_pk_bf16_f32 %0, %1, %2" : "=v"(d) : "v"(lo), "v"(hi));
  return d;
}

// v_permlane32_swap_b32: x[32..63] <- y_old[0..31]; y[0..31] <- x_old[32..63]
static DEV void pl32(unsigned& x, unsigned& y) {
  asm("v_permlane32_swap_b32 %0, %1" : "+v"(x), "+v"(y));
}

// ---------------- W [K][N] f32 -> Wt [N][K] bf16 (transpose + convert) ----------------
__global__ __launch_bounds__(256) void wtrans(const float* __restrict__ W,
                                              unsigned short* __restrict__ Wt) {
  __shared__ __align__(16) unsigned short T[64][72];
  const int tid = threadIdx.x;
  const int k0 = blockIdx.x * 64, n0 = blockIdx.y * 64;
  const int r = tid >> 4, c4 = (tid & 15) * 4;
  for (int j = 0; j < 4; ++j) {
    int row = j * 16 + r;
    float4 v = *(const float4*)&W[(size_t)(k0 + row) * 1024 + n0 + c4];
    ushort4 w;
    w.x = f2bf(v.x); w.y = f2bf(v.y); w.z = f2bf(v.z); w.w = f2bf(v.w);
    *(ushort4*)&T[row][c4] = w;
  }
  __syncthreads();
  for (int j = 0; j < 4; ++j) {
    int n = j * 16 + r;
    ushort4 w;
    w.x = T[c4 + 0][n]; w.y = T[c4 + 1][n]; w.z = T[c4 + 2][n]; w.w = T[c4 + 3][n];
    *(ushort4*)&Wt[(size_t)(n0 + n) * 1024 + k0 + c4] = w;
  }
}

// ---------------- GEMM: Y[M][1024] = X[M][1024] @ W + bias ----------------
template <typename InT, typename OutT>
__global__ __launch_bounds__(256) void gemm_bias(const InT* __restrict__ X,
                                                 const unsigned short* __restrict__ Wt,
                                                 const float* __restrict__ bias,
                                                 OutT* __restrict__ Y) {
  constexpr int KP = 72;
  __shared__ __align__(16) unsigned short As[128 * KP];
  __shared__ __align__(16) unsigned short Bs[128 * KP];
  const int tid = threadIdx.x, lane = tid & 63, wid = tid >> 6;
  const int m0 = blockIdx.x * 128, n0 = blockIdx.y * 128;
  const int wm = (wid >> 1) * 64, wn = (wid & 1) * 64;
  f32x4 acc[4][4] = {};

  for (int k0 = 0; k0 < 1024; k0 += 64) {
    __syncthreads();
    {
      const int r = tid >> 4, c4 = (tid & 15) * 4;
      for (int j = 0; j < 8; ++j) {
        const int row = j * 16 + r;
        ushort4 w;
        if constexpr (std::is_same_v<InT, float>) {
          float4 v = *(const float4*)&X[(size_t)(m0 + row) * 1024 + k0 + c4];
          w.x = f2bf(v.x); w.y = f2bf(v.y); w.z = f2bf(v.z); w.w = f2bf(v.w);
        } else {
          w = *(const ushort4*)&X[(size_t)(m0 + row) * 1024 + k0 + c4];
        }
        *(ushort4*)&As[row * KP + c4] = w;
      }
      const int r2 = tid >> 3, c8 = (tid & 7) * 8;
      for (int j = 0; j < 4; ++j) {
        const int n = j * 32 + r2;
        *(uint4*)&Bs[n * KP + c8] = *(const uint4*)&Wt[(size_t)(n0 + n) * 1024 + k0 + c8];
      }
    }
    __syncthreads();
    for (int kk = 0; kk < 2; ++kk) {
      const int kb = kk * 32 + (lane >> 4) * 8;
      bf16x8 af[4], bfr[4];
      for (int i = 0; i < 4; ++i)
        af[i] = *(const bf16x8*)&As[(wm + i * 16 + (lane & 15)) * KP + kb];
      for (int i = 0; i < 4; ++i)
        bfr[i] = *(const bf16x8*)&Bs[(wn + i * 16 + (lane & 15)) * KP + kb];
      for (int mi = 0; mi < 4; ++mi)
        for (int ni = 0; ni < 4; ++ni)
          acc[mi][ni] =
              __builtin_amdgcn_mfma_f32_16x16x32_bf16(af[mi], bfr[ni], acc[mi][ni], 0, 0, 0);
    }
  }
  for (int ni = 0; ni < 4; ++ni) {
    const int col = n0 + wn + ni * 16 + (lane & 15);
    const float bv = bias[col];
    for (int mi = 0; mi < 4; ++mi) {
      const int row = m0 + wm + mi * 16 + (lane >> 4) * 4;
      for (int r = 0; r < 4; ++r) {
        float v = acc[mi][ni][r] + bv;
        if constexpr (std::is_same_v<OutT, float>)
          Y[(size_t)(row + r) * 1024 + col] = v;
        else
          Y[(size_t)(row + r) * 1024 + col] = f2bf(v);
      }
    }
  }
}

// ---------------- causal flash attention (swapped-operand 32x32 MFMA) ----------------
// S^T = mfma(K, Q): lane owns q-col (lane&31); softmax stats are lane-scalars.
// O^T = mfma(V^T, P^T): col=q matches, so alpha/l rescale is lane-scalar.
// grid: (S/128 heavy-first, B*H). block: 256 = 4 waves x 32 q-rows. KVBLK=64.
__global__ __launch_bounds__(256) void attn_fwd(const unsigned short* __restrict__ Qb,
                                                const unsigned short* __restrict__ Kb,
                                                const unsigned short* __restrict__ Vb,
                                                unsigned short* __restrict__ Ob) {
  constexpr int KP = 72;  // 144B pitch: 16B aligned, bank-balanced for b128 reads
  __shared__ __align__(16) unsigned short SM[2 * 64 * KP];
  unsigned short* Ks  = SM;            // [64 kv][72 d-pitch]
  unsigned short* Vts = SM + 64 * KP;  // [64 dv][72 kv-pitch]  (V transposed)
  const int tid = threadIdx.x, lane = tid & 63, wid = tid >> 6;
  const int l31 = lane & 31, hi = lane >> 5;
  const int q0 = (15 - blockIdx.x) * 128;  // heavy blocks dispatch first
  const int bh = blockIdx.y, b = bh >> 4, h = bh & 15;
  const size_t rowbase = (size_t)b * 2048;
  const int col0 = h * 64;
  const int qmin = q0 + wid * 32;
  const int myq = qmin + l31;

  // Q fragments in registers: B-operand [q=lane&31][d = c*16 + hi*8 + j]
  bf16x8 qf[4];
#pragma unroll
  for (int c = 0; c < 4; ++c)
    qf[c] = *(const bf16x8*)&Qb[(rowbase + myq) * 1024 + col0 + c * 16 + hi * 8];

  f32x16 o[2];
  o[0] = 0.f; o[1] = 0.f;
  float mrow = -1.0e30f, lrow = 0.f;
  const float L2E = 1.44269504f;

  for (int kv0 = 0; kv0 < q0 + 128; kv0 += 64) {
    __syncthreads();
    {
      // stage K [64][64] (rows 128B, perfectly coalesced)
      const int rr = tid >> 3, c8 = (tid & 7) * 8;
      *(uint4*)&Ks[rr * KP + c8] =
          *(const uint4*)&Kb[(rowbase + kv0 + rr) * 1024 + col0 + c8];
      *(uint4*)&Ks[(rr + 32) * KP + c8] =
          *(const uint4*)&Kb[(rowbase + kv0 + rr + 32) * 1024 + col0 + c8];
      // stage V transposed: pair p2 of kv rows, 8 dv each -> dword writes (~2-way)
      const int p2 = tid & 31, dv0 = (tid >> 5) * 8;
      union { uint4 v; unsigned short s[8]; } A, B;
      A.v = *(const uint4*)&Vb[(rowbase + kv0 + 2 * p2) * 1024 + col0 + dv0];
      B.v = *(const uint4*)&Vb[(rowbase + kv0 + 2 * p2 + 1) * 1024 + col0 + dv0];
#pragma unroll
      for (int i = 0; i < 8; ++i)
        *(unsigned*)&Vts[(dv0 + i) * KP + 2 * p2] =
            (unsigned)A.s[i] | ((unsigned)B.s[i] << 16);
    }
    __syncthreads();
    if (kv0 > qmin + 31) continue;  // wave fully past causal frontier

    // S^T[kv][q]: 2 kv-halves x 4 d-chunks of mfma_32x32x16
    f32x16 s2[2];
    s2[0] = 0.f; s2[1] = 0.f;
#pragma unroll
    for (int m = 0; m < 2; ++m)
#pragma unroll
      for (int c = 0; c < 4; ++c) {
        bf16x8 kf = *(const bf16x8*)&Ks[(m * 32 + l31) * KP + c * 16 + hi * 8];
        s2[m] = __builtin_amdgcn_mfma_f32_32x32x16_bf16(kf, qf[c], s2[m], 0, 0, 0);
      }

    // scale + causal mask (kv index = kv0 + m*32 + (r&3)+8*(r>>2)+4*hi; q = myq)
    if (kv0 + 63 > qmin) {
      const int thr = l31 + (qmin - kv0);
#pragma unroll
      for (int m = 0; m < 2; ++m)
#pragma unroll
        for (int r = 0; r < 16; ++r) {
          const int kvl = m * 32 + (r & 3) + 8 * (r >> 2) + 4 * hi;
          const float v = s2[m][r] * 0.125f;
          s2[m][r] = (kvl > thr) ? -1.0e30f : v;
        }
    } else {
#pragma unroll
      for (int m = 0; m < 2; ++m)
#pragma unroll
        for (int r = 0; r < 16; ++r) s2[m][r] *= 0.125f;
    }

    // online softmax: stats per lane (one q each); partner lane (^32) has other 32 kv
    float tmax = -1.0e30f;
#pragma unroll
    for (int m = 0; m < 2; ++m)
#pragma unroll
      for (int r = 0; r < 16; ++r) tmax = fmaxf(tmax, s2[m][r]);
    tmax = fmaxf(tmax, __shfl_xor(tmax, 32));
    const float mnew = fmaxf(mrow, tmax);
    const float al = exp2f((mrow - mnew) * L2E);
    float rs = 0.f;
#pragma unroll
    for (int m = 0; m < 2; ++m)
#pragma unroll
      for (int r = 0; r < 16; ++r) {
        const float pz = exp2f((s2[m][r] - mnew) * L2E);
        s2[m][r] = pz;
        rs += pz;
      }
    rs += __shfl_xor(rs, 32);
    lrow = lrow * al + rs;
    mrow = mnew;
    o[0] *= al;
    o[1] *= al;

    // P^T B-operand fragments in-register: cvt_pk pairs + permlane32_swap
    bf16x8 pf[4];
#pragma unroll
    for (int m = 0; m < 2; ++m) {
      unsigned a0 = cvtpk(s2[m][0], s2[m][1]), a1 = cvtpk(s2[m][2], s2[m][3]);
      unsigned b0 = cvtpk(s2[m][4], s2[m][5]), b1 = cvtpk(s2[m][6], s2[m][7]);
      pl32(a0, b0);
      pl32(a1, b1);
      pf[2 * m] = __builtin_bit_cast(bf16x8, (u32x4){a0, a1, b0, b1});
      unsigned c0 = cvtpk(s2[m][8], s2[m][9]), c1 = cvtpk(s2[m][10], s2[m][11]);
      unsigned d0 = cvtpk(s2[m][12], s2[m][13]), d1 = cvtpk(s2[m][14], s2[m][15]);
      pl32(c0, d0);
      pl32(c1, d1);
      pf[2 * m + 1] = __builtin_bit_cast(bf16x8, (u32x4){c0, c1, d0, d1});
    }

    // O^T[dv][q] += V^T[dv][kv] @ P^T[kv][q]
#pragma unroll
    for (int nt = 0; nt < 2; ++nt)
#pragma unroll
      for (int cc = 0; cc < 4; ++cc) {
        bf16x8 vf = *(const bf16x8*)&Vts[(nt * 32 + l31) * KP + cc * 16 + hi * 8];
        o[nt] = __builtin_amdgcn_mfma_f32_32x32x16_bf16(vf, pf[cc], o[nt], 0, 0, 0);
      }
  }

  // epilogue: O^T/l -> LDS transpose -> coalesced bf16 store
  __syncthreads();  // all waves done reading Ks/Vts
  unsigned short* Os = SM + wid * 32 * KP;  // per-wave [32 q][72 dv-pitch]
  const float inv = 1.0f / lrow;
#pragma unroll
  for (int nt = 0; nt < 2; ++nt)
#pragma unroll
    for (int rq = 0; rq < 4; ++rq)
#pragma unroll
      for (int j = 0; j < 2; ++j) {
        const int r = rq * 4 + 2 * j;
        const unsigned pk = cvtpk(o[nt][r] * inv, o[nt][r + 1] * inv);
        *(unsigned*)&Os[l31 * KP + nt * 32 + 8 * rq + 4 * hi + 2 * j] = pk;
      }
  __syncthreads();
#pragma unroll
  for (int i = 0; i < 4; ++i) {
    const int qq = (lane >> 3) + i * 8;
    const int dvc = (lane & 7) * 8;
    uint4 val = *(const uint4*)&Os[qq * KP + dvc];
    *(uint4*)&Ob[(rowbase + qmin + qq) * 1024 + col0 + dvc] = val;
  }
}

extern "C" void kernel_launch(void* const* d_in, const int* in_sizes, int n_in,
                              void* d_out, int out_size, void* d_ws, size_t ws_size,
                              hipStream_t stream) {
  const float* Q  = (const float*)d_in[0];
  const float* K  = (const float*)d_in[1];
  const float* V  = (const float*)d_in[2];
  // d_in[3] = mask: known causal tril, applied analytically in attn_fwd
  const float* Wq = (const float*)d_in[4];
  const float* bq = (const float*)d_in[5];
  const float* Wk = (const float*)d_in[6];
  const float* bk = (const float*)d_in[7];
  const float* Wv = (const float*)d_in[8];
  const float* bv = (const float*)d_in[9];
  const float* Wo = (const float*)d_in[10];
  const float* bo = (const float*)d_in[11];
  float* out = (float*)d_out;

  const size_t MB = 1024 * 1024;
  char* ws = (char*)d_ws;
  unsigned short* qb  = (unsigned short*)(ws + 0 * MB);
  unsigned short* kb  = (unsigned short*)(ws + 16 * MB);
  unsigned short* vbf = (unsigned short*)(ws + 32 * MB);
  unsigned short* ab  = (unsigned short*)(ws + 48 * MB);
  unsigned short* wtq = (unsigned short*)(ws + 64 * MB);
  unsigned short* wtk = (unsigned short*)(ws + 66 * MB);
  unsigned short* wtv = (unsigned short*)(ws + 68 * MB);
  unsigned short* wto = (unsigned short*)(ws + 70 * MB);

  dim3 tg(16, 16);
  wtrans<<<tg, 256, 0, stream>>>(Wq, wtq);
  wtrans<<<tg, 256, 0, stream>>>(Wk, wtk);
  wtrans<<<tg, 256, 0, stream>>>(Wv, wtv);
  wtrans<<<tg, 256, 0, stream>>>(Wo, wto);

  dim3 gg(64, 8);
  gemm_bias<float, unsigned short><<<gg, 256, 0, stream>>>(Q, wtq, bq, qb);
  gemm_bias<float, unsigned short><<<gg, 256, 0, stream>>>(K, wtk, bk, kb);
  gemm_bias<float, unsigned short><<<gg, 256, 0, stream>>>(V, wtv, bv, vbf);

  dim3 ag(16, 64);
  attn_fwd<<<ag, 256, 0, stream>>>(qb, kb, vbf, ab);

  gemm_bias<unsigned short, float><<<gg, 256, 0, stream>>>(ab, wto, bo, out);
}

// Round 3
// 274.183 us; speedup vs baseline: 1.8537x; 1.0977x over previous
//
#include <hip/hip_runtime.h>
#include <hip/hip_bf16.h>
#include <type_traits>

#define DEV __device__ __forceinline__

typedef short bf16x8 __attribute__((ext_vector_type(8)));
typedef float f32x4 __attribute__((ext_vector_type(4)));
typedef float f32x16 __attribute__((ext_vector_type(16)));
typedef unsigned u32x4 __attribute__((ext_vector_type(4)));

static DEV unsigned short f2bf(float f) {
  unsigned u = __builtin_bit_cast(unsigned, f);
  u += 0x7FFFu + ((u >> 16) & 1u);
  return (unsigned short)(u >> 16);
}

static DEV unsigned cvtpk(float lo, float hi) {
  unsigned d;
  asm("v_cvt_pk_bf16_f32 %0, %1, %2" : "=v"(d) : "v"(lo), "v"(hi));
  return d;
}

// v_permlane32_swap_b32: x[32..63] <- y_old[0..31]; y[0..31] <- x_old[32..63]
static DEV void pl32(unsigned& x, unsigned& y) {
  asm("v_permlane32_swap_b32 %0, %1" : "+v"(x), "+v"(y));
}

// ---------------- W [K][N] f32 -> Wt [N][K] bf16 (transpose + convert) ----------------
__global__ __launch_bounds__(256) void wtrans(const float* __restrict__ W,
                                              unsigned short* __restrict__ Wt) {
  __shared__ __align__(16) unsigned short T[64][72];
  const int tid = threadIdx.x;
  const int k0 = blockIdx.x * 64, n0 = blockIdx.y * 64;
  const int r = tid >> 4, c4 = (tid & 15) * 4;
  for (int j = 0; j < 4; ++j) {
    int row = j * 16 + r;
    float4 v = *(const float4*)&W[(size_t)(k0 + row) * 1024 + n0 + c4];
    ushort4 w;
    w.x = f2bf(v.x); w.y = f2bf(v.y); w.z = f2bf(v.z); w.w = f2bf(v.w);
    *(ushort4*)&T[row][c4] = w;
  }
  __syncthreads();
  for (int j = 0; j < 4; ++j) {
    int n = j * 16 + r;
    ushort4 w;
    w.x = T[c4 + 0][n]; w.y = T[c4 + 1][n]; w.z = T[c4 + 2][n]; w.w = T[c4 + 3][n];
    *(ushort4*)&Wt[(size_t)(n0 + n) * 1024 + k0 + c4] = w;
  }
}

// ---------------- V^T builder: vbf [B*S][1024] -> vt [bh*64+dv][2048] ----------------
__global__ __launch_bounds__(256) void vtrans(const unsigned short* __restrict__ vbf,
                                              unsigned short* __restrict__ vt) {
  __shared__ __align__(16) unsigned short T[64][72];
  const int tid = threadIdx.x;
  const int s0 = blockIdx.x * 64;
  const int bh = blockIdx.y, b = bh >> 4, h = bh & 15;
  const int col0 = h * 64;
  const int rr = tid >> 3, c8 = (tid & 7) * 8;
  for (int p = 0; p < 2; ++p) {
    const int row = rr + 32 * p;
    *(uint4*)&T[row][c8] =
        *(const uint4*)&vbf[((size_t)b * 2048 + s0 + row) * 1024 + col0 + c8];
  }
  __syncthreads();
  const int dv = tid & 63, ss = (tid >> 6) * 16;
  union { uint4 v[2]; unsigned short s[16]; } o;
#pragma unroll
  for (int i = 0; i < 16; ++i) o.s[i] = T[ss + i][dv];
  *(uint4*)&vt[((size_t)bh * 64 + dv) * 2048 + s0 + ss] = o.v[0];
  *(uint4*)&vt[((size_t)bh * 64 + dv) * 2048 + s0 + ss + 8] = o.v[1];
}

// ---------------- GEMM: Y[M][1024] = X[M][1024] @ W + bias ----------------
template <typename InT, typename OutT>
__global__ __launch_bounds__(256) void gemm_bias(const InT* __restrict__ X,
                                                 const unsigned short* __restrict__ Wt,
                                                 const float* __restrict__ bias,
                                                 OutT* __restrict__ Y) {
  constexpr int KP = 72;
  __shared__ __align__(16) unsigned short As[128 * KP];
  __shared__ __align__(16) unsigned short Bs[128 * KP];
  const int tid = threadIdx.x, lane = tid & 63, wid = tid >> 6;
  const int m0 = blockIdx.x * 128, n0 = blockIdx.y * 128;
  const int wm = (wid >> 1) * 64, wn = (wid & 1) * 64;
  f32x4 acc[4][4] = {};

  for (int k0 = 0; k0 < 1024; k0 += 64) {
    __syncthreads();
    {
      const int r = tid >> 4, c4 = (tid & 15) * 4;
      for (int j = 0; j < 8; ++j) {
        const int row = j * 16 + r;
        ushort4 w;
        if constexpr (std::is_same_v<InT, float>) {
          float4 v = *(const float4*)&X[(size_t)(m0 + row) * 1024 + k0 + c4];
          w.x = f2bf(v.x); w.y = f2bf(v.y); w.z = f2bf(v.z); w.w = f2bf(v.w);
        } else {
          w = *(const ushort4*)&X[(size_t)(m0 + row) * 1024 + k0 + c4];
        }
        *(ushort4*)&As[row * KP + c4] = w;
      }
      const int r2 = tid >> 3, c8 = (tid & 7) * 8;
      for (int j = 0; j < 4; ++j) {
        const int n = j * 32 + r2;
        *(uint4*)&Bs[n * KP + c8] = *(const uint4*)&Wt[(size_t)(n0 + n) * 1024 + k0 + c8];
      }
    }
    __syncthreads();
    for (int kk = 0; kk < 2; ++kk) {
      const int kb = kk * 32 + (lane >> 4) * 8;
      bf16x8 af[4], bfr[4];
      for (int i = 0; i < 4; ++i)
        af[i] = *(const bf16x8*)&As[(wm + i * 16 + (lane & 15)) * KP + kb];
      for (int i = 0; i < 4; ++i)
        bfr[i] = *(const bf16x8*)&Bs[(wn + i * 16 + (lane & 15)) * KP + kb];
      for (int mi = 0; mi < 4; ++mi)
        for (int ni = 0; ni < 4; ++ni)
          acc[mi][ni] =
              __builtin_amdgcn_mfma_f32_16x16x32_bf16(af[mi], bfr[ni], acc[mi][ni], 0, 0, 0);
    }
  }
  for (int ni = 0; ni < 4; ++ni) {
    const int col = n0 + wn + ni * 16 + (lane & 15);
    const float bv = bias[col];
    for (int mi = 0; mi < 4; ++mi) {
      const int row = m0 + wm + mi * 16 + (lane >> 4) * 4;
      for (int r = 0; r < 4; ++r) {
        float v = acc[mi][ni][r] + bv;
        if constexpr (std::is_same_v<OutT, float>)
          Y[(size_t)(row + r) * 1024 + col] = v;
        else
          Y[(size_t)(row + r) * 1024 + col] = f2bf(v);
      }
    }
  }
}

// ---------------- causal flash attention (swapped-operand, dbuf + async stage) --------
// grid: 1024 blocks 1-D (XCD/balance swizzled). block: 256 = 4 waves x 32 q-rows.
__global__ __launch_bounds__(256, 4) void attn_fwd(const unsigned short* __restrict__ Qb,
                                                   const unsigned short* __restrict__ Kb,
                                                   const unsigned short* __restrict__ Vt,
                                                   unsigned short* __restrict__ Ob) {
  constexpr int KP = 72;  // 144B pitch
  __shared__ __align__(16) unsigned short SM[4 * 64 * KP];  // 2 x (Ks + Vs), 36.8KB
  const int tid = threadIdx.x, lane = tid & 63, wid = tid >> 6;
  const int l31 = lane & 31, hi = lane >> 5;
  // swizzle: first 64 ids = heaviest q-block of every bh; same-bh -> same XCD;
  // stride-256 id sets mix qb weights for per-CU balance.
  const int id = blockIdx.x;
  const int xcd = id & 7, idx = id >> 3;
  const int bh = xcd + 8 * (idx & 7);
  const int qb = idx >> 3;
  const int q0 = (15 - qb) * 128;
  const int b = bh >> 4, h = bh & 15;
  const size_t rowbase = (size_t)b * 2048;
  const int col0 = h * 64;
  const int qmin = q0 + wid * 32;
  const int myq = qmin + l31;
  const unsigned short* Vrow = Vt + (size_t)bh * 64 * 2048;

  // Q fragments in registers: B-operand [q=lane&31][d = c*16 + hi*8 + j]
  bf16x8 qf[4];
#pragma unroll
  for (int c = 0; c < 4; ++c)
    qf[c] = *(const bf16x8*)&Qb[(rowbase + myq) * 1024 + col0 + c * 16 + hi * 8];

  f32x16 o[2];
  o[0] = 0.f; o[1] = 0.f;
  float mrow = -1.0e30f, lrow = 0.f;
  const float L2E = 1.44269504f;

  const int rr = tid >> 3, c8 = (tid & 7) * 8;
  const int ntiles = q0 / 64 + 2;
  uint4 kr0, kr1, vr0, vr1;
#define LOADT(KV0)                                                              \
  do {                                                                          \
    const int _k = (KV0);                                                       \
    kr0 = *(const uint4*)&Kb[(rowbase + _k + rr) * 1024 + col0 + c8];           \
    kr1 = *(const uint4*)&Kb[(rowbase + _k + rr + 32) * 1024 + col0 + c8];      \
    vr0 = *(const uint4*)&Vrow[(size_t)rr * 2048 + _k + c8];                    \
    vr1 = *(const uint4*)&Vrow[(size_t)(rr + 32) * 2048 + _k + c8];             \
  } while (0)

  LOADT(0);
  {  // prologue: stage tile 0 into buffer A, prefetch tile 1
    unsigned short* Ks = SM;
    *(uint4*)&Ks[rr * KP + c8] = kr0;
    *(uint4*)&Ks[(rr + 32) * KP + c8] = kr1;
    unsigned short* Vs = SM + 64 * KP;
    *(uint4*)&Vs[rr * KP + c8] = vr0;
    *(uint4*)&Vs[(rr + 32) * KP + c8] = vr1;
    LOADT(64);
    __syncthreads();
  }

  for (int t = 0; t < ntiles; ++t) {
    const int kv0 = t * 64;
    const int p = t & 1;
    // stage tile t+1 into the other buffer, then prefetch t+2
    if (t + 1 < ntiles) {
      unsigned short* Ks = SM + (p ^ 1) * 128 * KP;
      unsigned short* Vs = Ks + 64 * KP;
      *(uint4*)&Ks[rr * KP + c8] = kr0;
      *(uint4*)&Ks[(rr + 32) * KP + c8] = kr1;
      *(uint4*)&Vs[rr * KP + c8] = vr0;
      *(uint4*)&Vs[(rr + 32) * KP + c8] = vr1;
      if (t + 2 < ntiles) LOADT(kv0 + 128);
    }
    if (kv0 <= qmin + 31) {
      const unsigned short* Ks = SM + p * 128 * KP;
      const unsigned short* Vs = Ks + 64 * KP;

      // S^T[kv][q]
      f32x16 s2[2];
      s2[0] = 0.f; s2[1] = 0.f;
      __builtin_amdgcn_s_setprio(1);
#pragma unroll
      for (int m = 0; m < 2; ++m)
#pragma unroll
        for (int c = 0; c < 4; ++c) {
          bf16x8 kf = *(const bf16x8*)&Ks[(m * 32 + l31) * KP + c * 16 + hi * 8];
          s2[m] = __builtin_amdgcn_mfma_f32_32x32x16_bf16(kf, qf[c], s2[m], 0, 0, 0);
        }
      __builtin_amdgcn_s_setprio(0);

      // scale + causal mask
      if (kv0 + 63 > qmin) {
        const int thr = l31 + (qmin - kv0);
#pragma unroll
        for (int m = 0; m < 2; ++m)
#pragma unroll
          for (int r = 0; r < 16; ++r) {
            const int kvl = m * 32 + (r & 3) + 8 * (r >> 2) + 4 * hi;
            const float v = s2[m][r] * 0.125f;
            s2[m][r] = (kvl > thr) ? -1.0e30f : v;
          }
      } else {
#pragma unroll
        for (int m = 0; m < 2; ++m)
#pragma unroll
          for (int r = 0; r < 16; ++r) s2[m][r] *= 0.125f;
      }

      // online softmax, defer-max (T13)
      float tmax = -1.0e30f;
#pragma unroll
      for (int m = 0; m < 2; ++m)
#pragma unroll
        for (int r = 0; r < 16; ++r) tmax = fmaxf(tmax, s2[m][r]);
      tmax = fmaxf(tmax, __shfl_xor(tmax, 32));
      if (__any(tmax > mrow + 8.0f)) {
        const float mnew = fmaxf(mrow, tmax);
        const float al = exp2f((mrow - mnew) * L2E);
        mrow = mnew;
        lrow *= al;
        o[0] *= al;
        o[1] *= al;
      }
      float rs = 0.f;
#pragma unroll
      for (int m = 0; m < 2; ++m)
#pragma unroll
        for (int r = 0; r < 16; ++r) {
          const float pz = exp2f((s2[m][r] - mrow) * L2E);
          s2[m][r] = pz;
          rs += pz;
        }
      rs += __shfl_xor(rs, 32);
      lrow += rs;

      // P^T fragments in-register
      bf16x8 pf[4];
#pragma unroll
      for (int m = 0; m < 2; ++m) {
        unsigned a0 = cvtpk(s2[m][0], s2[m][1]), a1 = cvtpk(s2[m][2], s2[m][3]);
        unsigned b0 = cvtpk(s2[m][4], s2[m][5]), b1 = cvtpk(s2[m][6], s2[m][7]);
        pl32(a0, b0);
        pl32(a1, b1);
        pf[2 * m] = __builtin_bit_cast(bf16x8, (u32x4){a0, a1, b0, b1});
        unsigned c0 = cvtpk(s2[m][8], s2[m][9]), c1 = cvtpk(s2[m][10], s2[m][11]);
        unsigned d0 = cvtpk(s2[m][12], s2[m][13]), d1 = cvtpk(s2[m][14], s2[m][15]);
        pl32(c0, d0);
        pl32(c1, d1);
        pf[2 * m + 1] = __builtin_bit_cast(bf16x8, (u32x4){c0, c1, d0, d1});
      }

      // O^T[dv][q] += V^T[dv][kv] @ P^T[kv][q]
      __builtin_amdgcn_s_setprio(1);
#pragma unroll
      for (int nt = 0; nt < 2; ++nt)
#pragma unroll
        for (int cc = 0; cc < 4; ++cc) {
          bf16x8 vf = *(const bf16x8*)&Vs[(nt * 32 + l31) * KP + cc * 16 + hi * 8];
          o[nt] = __builtin_amdgcn_mfma_f32_32x32x16_bf16(vf, pf[cc], o[nt], 0, 0, 0);
        }
      __builtin_amdgcn_s_setprio(0);
    }
    __syncthreads();
  }
#undef LOADT

  // epilogue: O^T/l -> LDS transpose -> coalesced bf16 store
  unsigned short* Os = SM + wid * 32 * KP;  // per-wave [32 q][72 dv-pitch]
  const float inv = 1.0f / lrow;
#pragma unroll
  for (int nt = 0; nt < 2; ++nt)
#pragma unroll
    for (int rq = 0; rq < 4; ++rq)
#pragma unroll
      for (int j = 0; j < 2; ++j) {
        const int r = rq * 4 + 2 * j;
        const unsigned pk = cvtpk(o[nt][r] * inv, o[nt][r + 1] * inv);
        *(unsigned*)&Os[l31 * KP + nt * 32 + 8 * rq + 4 * hi + 2 * j] = pk;
      }
  __syncthreads();
#pragma unroll
  for (int i = 0; i < 4; ++i) {
    const int qq = (lane >> 3) + i * 8;
    const int dvc = (lane & 7) * 8;
    uint4 val = *(const uint4*)&Os[qq * KP + dvc];
    *(uint4*)&Ob[(rowbase + qmin + qq) * 1024 + col0 + dvc] = val;
  }
}

extern "C" void kernel_launch(void* const* d_in, const int* in_sizes, int n_in,
                              void* d_out, int out_size, void* d_ws, size_t ws_size,
                              hipStream_t stream) {
  const float* Q  = (const float*)d_in[0];
  const float* K  = (const float*)d_in[1];
  const float* V  = (const float*)d_in[2];
  // d_in[3] = mask: known causal tril, applied analytically in attn_fwd
  const float* Wq = (const float*)d_in[4];
  const float* bq = (const float*)d_in[5];
  const float* Wk = (const float*)d_in[6];
  const float* bk = (const float*)d_in[7];
  const float* Wv = (const float*)d_in[8];
  const float* bv = (const float*)d_in[9];
  const float* Wo = (const float*)d_in[10];
  const float* bo = (const float*)d_in[11];
  float* out = (float*)d_out;

  const size_t MB = 1024 * 1024;
  char* ws = (char*)d_ws;
  unsigned short* qb  = (unsigned short*)(ws + 0 * MB);   // [8192][1024] bf16
  unsigned short* kb  = (unsigned short*)(ws + 16 * MB);
  unsigned short* vbf = (unsigned short*)(ws + 32 * MB);  // V proj; later reused as attn out
  unsigned short* vt  = (unsigned short*)(ws + 48 * MB);  // V^T [64bh*64dv][2048]
  unsigned short* wtq = (unsigned short*)(ws + 64 * MB);
  unsigned short* wtk = (unsigned short*)(ws + 66 * MB);
  unsigned short* wtv = (unsigned short*)(ws + 68 * MB);
  unsigned short* wto = (unsigned short*)(ws + 70 * MB);
  unsigned short* ob  = vbf;  // attn output overwrites dead V-proj buffer

  dim3 tg(16, 16);
  wtrans<<<tg, 256, 0, stream>>>(Wq, wtq);
  wtrans<<<tg, 256, 0, stream>>>(Wk, wtk);
  wtrans<<<tg, 256, 0, stream>>>(Wv, wtv);
  wtrans<<<tg, 256, 0, stream>>>(Wo, wto);

  dim3 gg(64, 8);
  gemm_bias<float, unsigned short><<<gg, 256, 0, stream>>>(Q, wtq, bq, qb);
  gemm_bias<float, unsigned short><<<gg, 256, 0, stream>>>(K, wtk, bk, kb);
  gemm_bias<float, unsigned short><<<gg, 256, 0, stream>>>(V, wtv, bv, vbf);

  vtrans<<<dim3(32, 64), 256, 0, stream>>>(vbf, vt);

  attn_fwd<<<1024, 256, 0, stream>>>(qb, kb, vt, ob);

  gemm_bias<unsigned short, float><<<gg, 256, 0, stream>>>(ob, wto, bo, out);
}

// Round 4
// 226.647 us; speedup vs baseline: 2.2426x; 1.2097x over previous
//
#include <hip/hip_runtime.h>
#include <hip/hip_bf16.h>
#include <type_traits>

#define DEV __device__ __forceinline__

typedef short bf16x8 __attribute__((ext_vector_type(8)));
typedef float f32x4 __attribute__((ext_vector_type(4)));
typedef float f32x16 __attribute__((ext_vector_type(16)));
typedef unsigned u32x4 __attribute__((ext_vector_type(4)));

static DEV unsigned short f2bf(float f) {
  unsigned u = __builtin_bit_cast(unsigned, f);
  u += 0x7FFFu + ((u >> 16) & 1u);
  return (unsigned short)(u >> 16);
}

static DEV unsigned cvtpk(float lo, float hi) {
  unsigned d;
  asm("v_cvt_pk_bf16_f32 %0, %1, %2" : "=v"(d) : "v"(lo), "v"(hi));
  return d;
}

// v_permlane32_swap_b32: x[32..63] <- y_old[0..31]; y[0..31] <- x_old[32..63]
static DEV void pl32(unsigned& x, unsigned& y) {
  asm("v_permlane32_swap_b32 %0, %1" : "+v"(x), "+v"(y));
}

// ---------------- W [K][N] f32 -> Wt [N][K] bf16 (transpose + convert), 4 fused -------
__global__ __launch_bounds__(256) void wtrans4(const float* __restrict__ W0,
                                               const float* __restrict__ W1,
                                               const float* __restrict__ W2,
                                               const float* __restrict__ W3,
                                               unsigned short* __restrict__ T0,
                                               unsigned short* __restrict__ T1,
                                               unsigned short* __restrict__ T2,
                                               unsigned short* __restrict__ T3) {
  const int z = blockIdx.z;
  const float* W = z == 0 ? W0 : z == 1 ? W1 : z == 2 ? W2 : W3;
  unsigned short* Wt = z == 0 ? T0 : z == 1 ? T1 : z == 2 ? T2 : T3;
  __shared__ __align__(16) unsigned short T[64][72];
  const int tid = threadIdx.x;
  const int k0 = blockIdx.x * 64, n0 = blockIdx.y * 64;
  const int r = tid >> 4, c4 = (tid & 15) * 4;
  for (int j = 0; j < 4; ++j) {
    int row = j * 16 + r;
    float4 v = *(const float4*)&W[(size_t)(k0 + row) * 1024 + n0 + c4];
    ushort4 w;
    w.x = f2bf(v.x); w.y = f2bf(v.y); w.z = f2bf(v.z); w.w = f2bf(v.w);
    *(ushort4*)&T[row][c4] = w;
  }
  __syncthreads();
  for (int j = 0; j < 4; ++j) {
    int n = j * 16 + r;
    ushort4 w;
    w.x = T[c4 + 0][n]; w.y = T[c4 + 1][n]; w.z = T[c4 + 2][n]; w.w = T[c4 + 3][n];
    *(ushort4*)&Wt[(size_t)(n0 + n) * 1024 + k0 + c4] = w;
  }
}

// ---------------- V^T builder: vbf [B*S][1024] -> vt [bh*64+dv][2048] ----------------
__global__ __launch_bounds__(256) void vtrans(const unsigned short* __restrict__ vbf,
                                              unsigned short* __restrict__ vt) {
  __shared__ __align__(16) unsigned short T[64][72];
  const int tid = threadIdx.x;
  const int s0 = blockIdx.x * 64;
  const int bh = blockIdx.y, b = bh >> 4, h = bh & 15;
  const int col0 = h * 64;
  const int rr = tid >> 3, c8 = (tid & 7) * 8;
  for (int p = 0; p < 2; ++p) {
    const int row = rr + 32 * p;
    *(uint4*)&T[row][c8] =
        *(const uint4*)&vbf[((size_t)b * 2048 + s0 + row) * 1024 + col0 + c8];
  }
  __syncthreads();
  const int dv = tid & 63, ss = (tid >> 6) * 16;
  union { uint4 v[2]; unsigned short s[16]; } o;
#pragma unroll
  for (int i = 0; i < 16; ++i) o.s[i] = T[ss + i][dv];
  *(uint4*)&vt[((size_t)bh * 64 + dv) * 2048 + s0 + ss] = o.v[0];
  *(uint4*)&vt[((size_t)bh * 64 + dv) * 2048 + s0 + ss + 8] = o.v[1];
}

// ---------------- GEMM core: Y[M][1024] = X[M][1024] @ Wt^T + bias ----------------
template <typename InT, typename OutT>
DEV void gemm_body(const InT* __restrict__ X, const unsigned short* __restrict__ Wt,
                   const float* __restrict__ bias, OutT* __restrict__ Y) {
  constexpr int KP = 72;
  __shared__ __align__(16) unsigned short As[128 * KP];
  __shared__ __align__(16) unsigned short Bs[128 * KP];
  const int tid = threadIdx.x, lane = tid & 63, wid = tid >> 6;
  const int m0 = blockIdx.x * 128, n0 = blockIdx.y * 128;
  const int wm = (wid >> 1) * 64, wn = (wid & 1) * 64;
  f32x4 acc[4][4] = {};

  for (int k0 = 0; k0 < 1024; k0 += 64) {
    __syncthreads();
    {
      const int r = tid >> 4, c4 = (tid & 15) * 4;
      for (int j = 0; j < 8; ++j) {
        const int row = j * 16 + r;
        ushort4 w;
        if constexpr (std::is_same_v<InT, float>) {
          float4 v = *(const float4*)&X[(size_t)(m0 + row) * 1024 + k0 + c4];
          w.x = f2bf(v.x); w.y = f2bf(v.y); w.z = f2bf(v.z); w.w = f2bf(v.w);
        } else {
          w = *(const ushort4*)&X[(size_t)(m0 + row) * 1024 + k0 + c4];
        }
        *(ushort4*)&As[row * KP + c4] = w;
      }
      const int r2 = tid >> 3, c8 = (tid & 7) * 8;
      for (int j = 0; j < 4; ++j) {
        const int n = j * 32 + r2;
        *(uint4*)&Bs[n * KP + c8] = *(const uint4*)&Wt[(size_t)(n0 + n) * 1024 + k0 + c8];
      }
    }
    __syncthreads();
    for (int kk = 0; kk < 2; ++kk) {
      const int kb = kk * 32 + (lane >> 4) * 8;
      bf16x8 af[4], bfr[4];
      for (int i = 0; i < 4; ++i)
        af[i] = *(const bf16x8*)&As[(wm + i * 16 + (lane & 15)) * KP + kb];
      for (int i = 0; i < 4; ++i)
        bfr[i] = *(const bf16x8*)&Bs[(wn + i * 16 + (lane & 15)) * KP + kb];
      for (int mi = 0; mi < 4; ++mi)
        for (int ni = 0; ni < 4; ++ni)
          acc[mi][ni] =
              __builtin_amdgcn_mfma_f32_16x16x32_bf16(af[mi], bfr[ni], acc[mi][ni], 0, 0, 0);
    }
  }
  for (int ni = 0; ni < 4; ++ni) {
    const int col = n0 + wn + ni * 16 + (lane & 15);
    const float bv = bias[col];
    for (int mi = 0; mi < 4; ++mi) {
      const int row = m0 + wm + mi * 16 + (lane >> 4) * 4;
      for (int r = 0; r < 4; ++r) {
        float v = acc[mi][ni][r] + bv;
        if constexpr (std::is_same_v<OutT, float>)
          Y[(size_t)(row + r) * 1024 + col] = v;
        else
          Y[(size_t)(row + r) * 1024 + col] = f2bf(v);
      }
    }
  }
}

// fused Q/K/V projection (z selects which)
__global__ __launch_bounds__(256) void gemm_qkv(
    const float* __restrict__ X0, const float* __restrict__ X1, const float* __restrict__ X2,
    const unsigned short* __restrict__ W0, const unsigned short* __restrict__ W1,
    const unsigned short* __restrict__ W2, const float* __restrict__ b0,
    const float* __restrict__ b1, const float* __restrict__ b2,
    unsigned short* __restrict__ Y0, unsigned short* __restrict__ Y1,
    unsigned short* __restrict__ Y2) {
  const int z = blockIdx.z;
  const float* X = z == 0 ? X0 : z == 1 ? X1 : X2;
  const unsigned short* Wt = z == 0 ? W0 : z == 1 ? W1 : W2;
  const float* bias = z == 0 ? b0 : z == 1 ? b1 : b2;
  unsigned short* Y = z == 0 ? Y0 : z == 1 ? Y1 : Y2;
  gemm_body<float, unsigned short>(X, Wt, bias, Y);
}

__global__ __launch_bounds__(256) void gemm_out(const unsigned short* __restrict__ X,
                                                const unsigned short* __restrict__ Wt,
                                                const float* __restrict__ bias,
                                                float* __restrict__ Y) {
  gemm_body<unsigned short, float>(X, Wt, bias, Y);
}

// ---------------- causal flash attention (swapped-operand, dbuf, compute-first) -------
// grid: 1024 blocks 1-D (XCD/balance swizzled). block: 256 = 4 waves x 32 q-rows.
__global__ __launch_bounds__(256) void attn_fwd(const unsigned short* __restrict__ Qb,
                                                const unsigned short* __restrict__ Kb,
                                                const unsigned short* __restrict__ Vt,
                                                unsigned short* __restrict__ Ob) {
  constexpr int KP = 72;  // 144B pitch
  __shared__ __align__(16) unsigned short SM[4 * 64 * KP];  // 2 x (Ks + Vs), 36.9KB
  const int tid = threadIdx.x, lane = tid & 63, wid = tid >> 6;
  const int l31 = lane & 31, hi = lane >> 5;
  const int id = blockIdx.x;
  const int xcd = id & 7, idx = id >> 3;
  const int bh = xcd + 8 * (idx & 7);
  const int qb = idx >> 3;
  const int q0 = (15 - qb) * 128;  // heavy blocks dispatch first
  const int b = bh >> 4, h = bh & 15;
  const size_t rowbase = (size_t)b * 2048;
  const int col0 = h * 64;
  const int qmin = q0 + wid * 32;
  const int myq = qmin + l31;
  const unsigned short* Vrow = Vt + (size_t)bh * 64 * 2048;

  // Q fragments in registers: B-operand [q=lane&31][d = c*16 + hi*8 + j]
  bf16x8 qf[4];
#pragma unroll
  for (int c = 0; c < 4; ++c)
    qf[c] = *(const bf16x8*)&Qb[(rowbase + myq) * 1024 + col0 + c * 16 + hi * 8];

  f32x16 o[2];
  o[0] = 0.f; o[1] = 0.f;
  float mrow = -1.0e30f, lrow = 0.f;
  const float L2E = 1.44269504f;

  const int rr = tid >> 3, c8 = (tid & 7) * 8;
  const int ntiles = q0 / 64 + 2;
  uint4 kr0, kr1, vr0, vr1;
#define LOADT(KV0)                                                              \
  do {                                                                          \
    const int _k = (KV0);                                                       \
    kr0 = *(const uint4*)&Kb[(rowbase + _k + rr) * 1024 + col0 + c8];           \
    kr1 = *(const uint4*)&Kb[(rowbase + _k + rr + 32) * 1024 + col0 + c8];      \
    vr0 = *(const uint4*)&Vrow[(size_t)rr * 2048 + _k + c8];                    \
    vr1 = *(const uint4*)&Vrow[(size_t)(rr + 32) * 2048 + _k + c8];             \
  } while (0)

  LOADT(0);
  {  // prologue: stage tile 0 into buffer A, prefetch tile 1
    unsigned short* Ks = SM;
    unsigned short* Vs = SM + 64 * KP;
    *(uint4*)&Ks[rr * KP + c8] = kr0;
    *(uint4*)&Ks[(rr + 32) * KP + c8] = kr1;
    *(uint4*)&Vs[rr * KP + c8] = vr0;
    *(uint4*)&Vs[(rr + 32) * KP + c8] = vr1;
    LOADT(64);
    __syncthreads();
  }

  for (int t = 0; t < ntiles; ++t) {
    const int kv0 = t * 64;
    const int p = t & 1;
    // ---- compute tile t from buffer p (before staging: keeps lgkmcnt clean) ----
    if (kv0 <= qmin + 31) {
      const unsigned short* Ks = SM + p * 128 * KP;
      const unsigned short* Vs = Ks + 64 * KP;

      // S^T[kv][q]
      f32x16 s2[2];
      s2[0] = 0.f; s2[1] = 0.f;
      __builtin_amdgcn_s_setprio(1);
#pragma unroll
      for (int m = 0; m < 2; ++m)
#pragma unroll
        for (int c = 0; c < 4; ++c) {
          bf16x8 kf = *(const bf16x8*)&Ks[(m * 32 + l31) * KP + c * 16 + hi * 8];
          s2[m] = __builtin_amdgcn_mfma_f32_32x32x16_bf16(kf, qf[c], s2[m], 0, 0, 0);
        }
      __builtin_amdgcn_s_setprio(0);

      // scale + causal mask
      if (kv0 + 63 > qmin) {
        const int thr = l31 + (qmin - kv0);
#pragma unroll
        for (int m = 0; m < 2; ++m)
#pragma unroll
          for (int r = 0; r < 16; ++r) {
            const int kvl = m * 32 + (r & 3) + 8 * (r >> 2) + 4 * hi;
            const float v = s2[m][r] * 0.125f;
            s2[m][r] = (kvl > thr) ? -1.0e30f : v;
          }
      } else {
#pragma unroll
        for (int m = 0; m < 2; ++m)
#pragma unroll
          for (int r = 0; r < 16; ++r) s2[m][r] *= 0.125f;
      }

      // online softmax, defer-max (T13)
      float tmax = -1.0e30f;
#pragma unroll
      for (int m = 0; m < 2; ++m)
#pragma unroll
        for (int r = 0; r < 16; ++r) tmax = fmaxf(tmax, s2[m][r]);
      tmax = fmaxf(tmax, __shfl_xor(tmax, 32));
      if (__any(tmax > mrow + 8.0f)) {
        const float mnew = fmaxf(mrow, tmax);
        const float al = exp2f((mrow - mnew) * L2E);
        mrow = mnew;
        lrow *= al;
        o[0] *= al;
        o[1] *= al;
      }
      float rs = 0.f;
#pragma unroll
      for (int m = 0; m < 2; ++m)
#pragma unroll
        for (int r = 0; r < 16; ++r) {
          const float pz = exp2f((s2[m][r] - mrow) * L2E);
          s2[m][r] = pz;
          rs += pz;
        }
      rs += __shfl_xor(rs, 32);
      lrow += rs;

      // P^T fragments in-register (cvt_pk + permlane32_swap)
      bf16x8 pf[4];
#pragma unroll
      for (int m = 0; m < 2; ++m) {
        unsigned a0 = cvtpk(s2[m][0], s2[m][1]), a1 = cvtpk(s2[m][2], s2[m][3]);
        unsigned b0 = cvtpk(s2[m][4], s2[m][5]), b1 = cvtpk(s2[m][6], s2[m][7]);
        pl32(a0, b0);
        pl32(a1, b1);
        pf[2 * m] = __builtin_bit_cast(bf16x8, (u32x4){a0, a1, b0, b1});
        unsigned c0 = cvtpk(s2[m][8], s2[m][9]), c1 = cvtpk(s2[m][10], s2[m][11]);
        unsigned d0 = cvtpk(s2[m][12], s2[m][13]), d1 = cvtpk(s2[m][14], s2[m][15]);
        pl32(c0, d0);
        pl32(c1, d1);
        pf[2 * m + 1] = __builtin_bit_cast(bf16x8, (u32x4){c0, c1, d0, d1});
      }

      // O^T[dv][q] += V^T[dv][kv] @ P^T[kv][q]
      __builtin_amdgcn_s_setprio(1);
#pragma unroll
      for (int nt = 0; nt < 2; ++nt)
#pragma unroll
        for (int cc = 0; cc < 4; ++cc) {
          bf16x8 vf = *(const bf16x8*)&Vs[(nt * 32 + l31) * KP + cc * 16 + hi * 8];
          o[nt] = __builtin_amdgcn_mfma_f32_32x32x16_bf16(vf, pf[cc], o[nt], 0, 0, 0);
        }
      __builtin_amdgcn_s_setprio(0);
    }
    // ---- stage tile t+1 into buffer p^1, then prefetch t+2 ----
    if (t + 1 < ntiles) {
      unsigned short* Ks = SM + (p ^ 1) * 128 * KP;
      unsigned short* Vs = Ks + 64 * KP;
      *(uint4*)&Ks[rr * KP + c8] = kr0;
      *(uint4*)&Ks[(rr + 32) * KP + c8] = kr1;
      *(uint4*)&Vs[rr * KP + c8] = vr0;
      *(uint4*)&Vs[(rr + 32) * KP + c8] = vr1;
      if (t + 2 < ntiles) LOADT(kv0 + 128);
    }
    __syncthreads();
  }
#undef LOADT

  // epilogue: O^T/l -> LDS transpose -> coalesced bf16 store
  unsigned short* Os = SM + wid * 32 * KP;  // per-wave [32 q][72 dv-pitch]
  const float inv = 1.0f / lrow;
#pragma unroll
  for (int nt = 0; nt < 2; ++nt)
#pragma unroll
    for (int rq = 0; rq < 4; ++rq)
#pragma unroll
      for (int j = 0; j < 2; ++j) {
        const int r = rq * 4 + 2 * j;
        const unsigned pk = cvtpk(o[nt][r] * inv, o[nt][r + 1] * inv);
        *(unsigned*)&Os[l31 * KP + nt * 32 + 8 * rq + 4 * hi + 2 * j] = pk;
      }
  __syncthreads();
#pragma unroll
  for (int i = 0; i < 4; ++i) {
    const int qq = (lane >> 3) + i * 8;
    const int dvc = (lane & 7) * 8;
    uint4 val = *(const uint4*)&Os[qq * KP + dvc];
    *(uint4*)&Ob[(rowbase + qmin + qq) * 1024 + col0 + dvc] = val;
  }
}

extern "C" void kernel_launch(void* const* d_in, const int* in_sizes, int n_in,
                              void* d_out, int out_size, void* d_ws, size_t ws_size,
                              hipStream_t stream) {
  const float* Q  = (const float*)d_in[0];
  const float* K  = (const float*)d_in[1];
  const float* V  = (const float*)d_in[2];
  // d_in[3] = mask: known causal tril, applied analytically in attn_fwd
  const float* Wq = (const float*)d_in[4];
  const float* bq = (const float*)d_in[5];
  const float* Wk = (const float*)d_in[6];
  const float* bk = (const float*)d_in[7];
  const float* Wv = (const float*)d_in[8];
  const float* bv = (const float*)d_in[9];
  const float* Wo = (const float*)d_in[10];
  const float* bo = (const float*)d_in[11];
  float* out = (float*)d_out;

  const size_t MB = 1024 * 1024;
  char* ws = (char*)d_ws;
  unsigned short* qb  = (unsigned short*)(ws + 0 * MB);   // [8192][1024] bf16
  unsigned short* kb  = (unsigned short*)(ws + 16 * MB);
  unsigned short* vbf = (unsigned short*)(ws + 32 * MB);  // V proj; later reused as attn out
  unsigned short* vt  = (unsigned short*)(ws + 48 * MB);  // V^T [64bh*64dv][2048]
  unsigned short* wtq = (unsigned short*)(ws + 64 * MB);
  unsigned short* wtk = (unsigned short*)(ws + 66 * MB);
  unsigned short* wtv = (unsigned short*)(ws + 68 * MB);
  unsigned short* wto = (unsigned short*)(ws + 70 * MB);
  unsigned short* ob  = vbf;  // attn output overwrites dead V-proj buffer

  wtrans4<<<dim3(16, 16, 4), 256, 0, stream>>>(Wq, Wk, Wv, Wo, wtq, wtk, wtv, wto);

  gemm_qkv<<<dim3(64, 8, 3), 256, 0, stream>>>(Q, K, V, wtq, wtk, wtv, bq, bk, bv,
                                               qb, kb, vbf);

  vtrans<<<dim3(32, 64), 256, 0, stream>>>(vbf, vt);

  attn_fwd<<<1024, 256, 0, stream>>>(qb, kb, vt, ob);

  gemm_out<<<dim3(64, 8), 256, 0, stream>>>(ob, wto, bo, out);
}